// Round 8
// baseline (238.580 us; speedup 1.0000x reference)
//
#include <hip/hip_runtime.h>

// GatedQueryAttLayer on MI355X (gfx950)
// B=16, S=512, E=1024, H=16, DK=64
// Pipeline (3 kernels): prep (inp->bf16 + W^T cvt + gate-weight image pack) ;
//   fused QKV GEMM + GATING (r12: gate weights pre-packed by prep, staged via
//   9 uniform GLL16 passes instead of per-block 12K cvt chain; r11 K-loop and
//   gate math byte-identical) ; flash attention (r10 structure).
// Scratch: gate image lives in d_out tail (written pre-proj, overwritten by attn).
// Workspace: 70 MB.

typedef __bf16 bf16;
typedef __bf16 bf16x8 __attribute__((ext_vector_type(8)));
typedef __bf16 bf16x4 __attribute__((ext_vector_type(4)));
typedef float  f32x4  __attribute__((ext_vector_type(4)));

#define MFMA16(a,b,c) __builtin_amdgcn_mfma_f32_16x16x32_bf16((a),(b),(c),0,0,0)

#define GLL16(gp, lp)                                                          \
  __builtin_amdgcn_global_load_lds(                                            \
      (__attribute__((address_space(1))) void*)(void*)(gp),                    \
      (__attribute__((address_space(3))) void*)(lp), 16, 0, 0)

// --------------------------------------------- prep: inp cvt + weight cvt/T
// bx<8192: fp32->bf16 input convert. bx<11264: W^T cvt. bx==11264: pack the
// gate-weight LDS image (Wfq^T|Wfk^T padded-72, Wfg^T padded-72, fp32 biases)
// so k_proj's epilogue can GLL16 it instead of re-transforming per block.
__global__ __launch_bounds__(256) void k_prep(const float* __restrict__ in,
                                              bf16* __restrict__ Xb,
                                              const float* __restrict__ Wq,
                                              const float* __restrict__ Wk,
                                              const float* __restrict__ Wv,
                                              bf16* __restrict__ WT,
                                              const float* __restrict__ Wfq,
                                              const float* __restrict__ bfq,
                                              const float* __restrict__ Wfk,
                                              const float* __restrict__ bfk,
                                              const float* __restrict__ Wfg,
                                              const float* __restrict__ bfg,
                                              bf16* __restrict__ gimg) {
  __shared__ float tile[32][33];
  const int bx = blockIdx.x, t = threadIdx.x;
  if (bx < 8192) {                       // conv: fp32 -> bf16, 4 elems/thread
    int i = bx * 256 + t;
    float4 v = ((const float4*)in)[i];
    bf16x4 o;
    o[0] = (bf16)v.x; o[1] = (bf16)v.y; o[2] = (bf16)v.z; o[3] = (bf16)v.w;
    ((bf16x4*)Xb)[i] = o;
  } else if (bx < 11264) {               // weight transpose + cvt
    int r = bx - 8192;
    int mat = r >> 10; r &= 1023;
    int kb = r >> 5, nb = r & 31;
    const float* W = (mat == 0) ? Wq : ((mat == 1) ? Wk : Wv);
    bf16* O = WT + (size_t)mat * (1024 * 1024);
    const int tr = t >> 3, tc = (t & 7) * 4;
    float4 v = *(const float4*)&W[(size_t)(kb * 32 + tr) * 1024 + nb * 32 + tc];
    tile[tr][tc] = v.x; tile[tr][tc + 1] = v.y;
    tile[tr][tc + 2] = v.z; tile[tr][tc + 3] = v.w;
    __syncthreads();
    bf16x4 o;
    o[0] = (bf16)tile[tc][tr];     o[1] = (bf16)tile[tc + 1][tr];
    o[2] = (bf16)tile[tc + 2][tr]; o[3] = (bf16)tile[tc + 3][tr];
    *(bf16x4*)&O[(size_t)(nb * 32 + tr) * 1024 + kb * 32 + tc] = o;
  } else {                               // gate-weight image pack (1 block)
    for (int idx = t; idx < 4096; idx += 256) {
      int k = idx >> 6, n = idx & 63;
      gimg[n * 72 + k]        = (bf16)Wfq[k * 64 + n];
      gimg[4608 + n * 72 + k] = (bf16)Wfk[k * 64 + n];
    }
    for (int idx = t; idx < 8192; idx += 256) {
      int k = idx >> 7, n = idx & 127;
      gimg[9216 + n * 72 + k] = (bf16)Wfg[k * 128 + n];
    }
    float* fb = (float*)(gimg + 18432);  // byte 36864: packed biases
    if (t < 64) { fb[t] = bfq[t]; fb[64 + t] = bfk[t]; }
    if (t < 128) fb[128 + t] = bfg[t];
  }
}

// ------------------------------------- fused QKV projection + gating GEMM
// r12: r11 structure; gate weights arrive pre-packed (gimg) and are staged
// with 9 uniform GLL16 passes issued right after the drain (fly under the
// v-store + sQ/sK register work). Gate math / LDS alias map unchanged.
__global__ __launch_bounds__(256, 2) void k_proj(const bf16* __restrict__ X,
                                                 const bf16* __restrict__ WT,
                                                 const float* __restrict__ bq,
                                                 const float* __restrict__ bk,
                                                 const float* __restrict__ bv,
                                                 const bf16* __restrict__ gimg,
                                                 bf16* __restrict__ qw,
                                                 bf16* __restrict__ kw,
                                                 bf16* __restrict__ vt) {
  extern __shared__ bf16 lds[];
  bf16* As = lds;            // 2 bufs x [128 rows][64 k] = 32 KiB
  bf16* Bs = lds + 16384;    // 2 bufs x [192 rows][64 k] = 48 KiB

  const int tid = threadIdx.x;
  const int m0 = blockIdx.x * 128;
  const int h  = blockIdx.y;             // head 0..15

  const int l = tid & 63, wid = tid >> 6;
  const int wm = wid >> 1, wn = wid & 1;          // 2M x 2N waves
  const int l4 = l & 15, q8 = l >> 4;
  const int cs0 = (q8 ^ (l4 & 7)) * 8;            // swizzled read col (kk=0)
  const int arow = (wm * 64 + l4) * 64;
  const int brow = (wn * 96 + l4) * 64;

  // staging: linear LDS dest (tid*16B), inverse-swizzled global source
  const int srow = tid >> 3;                      // 0..31 within a 32-row unit
  const int scol = ((tid & 7) ^ (srow & 7)) * 8;
  const bf16* Xs  = X  + (size_t)(m0 + srow) * 1024 + scol;
  const bf16* Wq_ = WT + (size_t)(h * 64 + srow) * 1024 + scol;
  const bf16* Wk_ = Wq_ + (size_t)1024 * 1024;
  const bf16* Wv_ = Wk_ + (size_t)1024 * 1024;
  const int ldst = tid * 8;

#define STG_AU(bf, kt, u)                                                      \
  GLL16(Xs + (size_t)(u) * 32768 + (kt) * 64,                                  \
        As + (bf) * 8192 + (u) * 2048 + ldst)
#define BSRC(u) ((u) < 2 ? Wq_ : ((u) < 4 ? Wk_ : Wv_))
#define STG_BU(bf, kt, u)                                                      \
  GLL16(BSRC(u) + (size_t)((u) & 1) * 32768 + (kt) * 64,                       \
        Bs + (bf) * 12288 + (u) * 2048 + ldst)

  f32x4 acc[4][6] = {};
  bf16x8 aa[2], bb0[6], bb1[6];

#define LDA2(bf, qm, kk)                                                       \
  do {                                                                         \
    _Pragma("unroll") for (int m_ = 0; m_ < 2; ++m_)                           \
        aa[m_] = *(const bf16x8*)&As[(bf) * 8192 + arow + (qm) * 2048 +        \
                                     m_ * 1024 + (cs0 ^ ((kk) * 32))];         \
  } while (0)
#define LDB6(bf, kk, arr)                                                      \
  do {                                                                         \
    _Pragma("unroll") for (int n_ = 0; n_ < 6; ++n_)                           \
        arr[n_] = *(const bf16x8*)&Bs[(bf) * 12288 + brow + n_ * 1024 +        \
                                      (cs0 ^ ((kk) * 32))];                    \
  } while (0)
#define MMQ(qm, arr)                                                           \
  do {                                                                         \
    _Pragma("unroll") for (int m_ = 0; m_ < 2; ++m_)                           \
    _Pragma("unroll") for (int n_ = 0; n_ < 6; ++n_)                           \
        acc[(qm) * 2 + m_][n_] =                                               \
            MFMA16(arr[n_], aa[m_], acc[(qm) * 2 + m_][n_]);                   \
  } while (0)
#define PH_PRE                                                                 \
  __builtin_amdgcn_s_barrier();                                                \
  asm volatile("s_waitcnt lgkmcnt(0)" ::: "memory");                           \
  __builtin_amdgcn_s_setprio(1)
#define PH_POST                                                                \
  __builtin_amdgcn_s_setprio(0);                                               \
  __builtin_amdgcn_s_barrier()

  // prologue: tile0 -> buf0 (A 4u + B 6u); tile1 B (6u) -> buf1.
  STG_AU(0, 0, 0); STG_AU(0, 0, 1); STG_AU(0, 0, 2); STG_AU(0, 0, 3);
  STG_BU(0, 0, 0); STG_BU(0, 0, 1); STG_BU(0, 0, 2);
  STG_BU(0, 0, 3); STG_BU(0, 0, 4); STG_BU(0, 0, 5);
  STG_BU(1, 1, 0); STG_BU(1, 1, 1); STG_BU(1, 1, 2);
  STG_BU(1, 1, 3); STG_BU(1, 1, 4); STG_BU(1, 1, 5);
  asm volatile("s_waitcnt vmcnt(6)" ::: "memory");
  __builtin_amdgcn_s_barrier();

#pragma unroll 1
  for (int i = 0; i < 8; ++i) {
    const int t1 = 2 * i + 1;
    const int t2 = (i < 7) ? 2 * i + 2 : 14;   // clamp: identical-byte restage
    const int t3 = (i < 7) ? 2 * i + 3 : 15;
    // ph1
    LDB6(0, 0, bb0); LDA2(0, 0, 0);
    STG_AU(1, t1, 0); STG_AU(1, t1, 1);
    PH_PRE; MMQ(0, bb0); PH_POST;
    // ph2
    LDB6(0, 1, bb1); LDA2(0, 1, 0);
    STG_AU(1, t1, 2); STG_AU(1, t1, 3);
    PH_PRE; MMQ(1, bb0); PH_POST;
    // ph3
    LDA2(0, 0, 1);
    STG_BU(0, t2, 0); STG_BU(0, t2, 1); STG_BU(0, t2, 2);
    PH_PRE; MMQ(0, bb1); PH_POST;
    // ph4
    LDA2(0, 1, 1);
    STG_BU(0, t2, 3); STG_BU(0, t2, 4); STG_BU(0, t2, 5);
    PH_PRE; MMQ(1, bb1);
    __builtin_amdgcn_s_setprio(0);
    asm volatile("s_waitcnt vmcnt(6)" ::: "memory");
    __builtin_amdgcn_s_barrier();
    // ph5
    LDB6(1, 0, bb0); LDA2(1, 0, 0);
    STG_AU(0, t2, 0); STG_AU(0, t2, 1);
    PH_PRE; MMQ(0, bb0); PH_POST;
    // ph6
    LDB6(1, 1, bb1); LDA2(1, 1, 0);
    STG_AU(0, t2, 2); STG_AU(0, t2, 3);
    PH_PRE; MMQ(1, bb0); PH_POST;
    // ph7
    LDA2(1, 0, 1);
    STG_BU(1, t3, 0); STG_BU(1, t3, 1); STG_BU(1, t3, 2);
    PH_PRE; MMQ(0, bb1); PH_POST;
    // ph8
    LDA2(1, 1, 1);
    STG_BU(1, t3, 3); STG_BU(1, t3, 4); STG_BU(1, t3, 5);
    PH_PRE; MMQ(1, bb1);
    __builtin_amdgcn_s_setprio(0);
    asm volatile("s_waitcnt vmcnt(6)" ::: "memory");
    __builtin_amdgcn_s_barrier();
  }

  // ================= fused gating epilogue (k_gate body) =================
  // Drain: 6 clamped restage GLL16s still in flight target As/Bs.
  asm volatile("s_waitcnt vmcnt(0)" ::: "memory");
  __syncthreads();

  char* gb = (char*)lds;                    // 80 KiB budget
  bf16* sQ  = (bf16*)gb;                    // [128][72] biased q   18432 B
  bf16* sK  = (bf16*)(gb + 18432);          // [128][72] biased k   18432 B
  bf16* sWq = (bf16*)(gb + 36864);          // [64][72]              9216 B
  bf16* sWk = (bf16*)(gb + 46080);          // [64][72]              9216 B
  bf16* sWg = (bf16*)(gb + 55296);          // [128][72]            18432 B
  float* sb = (float*)(gb + 73728);         // 256 floats            1024 B
  bf16* sG  = (bf16*)(gb + 36864);          // aliases sWq+sWk (dead post-GEMM1)
  bf16* Ms  = (bf16*)(gb + 36864);          // [128][136] aliases sG+sWg

  // gate weight image -> LDS: 9 uniform GLL16 passes (2304 chunks = 36864B,
  // exact sWq|sWk|sWg image). Issued first so they fly under the register
  // epilogue work below. Biases: 256 fp32 from image tail, one per thread.
#pragma unroll
  for (int p = 0; p < 9; ++p)
    GLL16(gimg + p * 2048 + tid * 8, (bf16*)(gb + 36864) + p * 2048 + tid * 8);
  sb[tid] = ((const float*)(gimg + 18432))[tid];

  // v store (biased) + biased q/k staged to LDS; acc dead afterwards.
#pragma unroll
  for (int mi = 0; mi < 4; ++mi) {
    const int tok = wm * 64 + mi * 16 + l4;
    const int m = m0 + tok;
    const int b_ = m >> 9, s = m & 511;
#pragma unroll
    for (int nj = 0; nj < 6; ++nj) {
      if (wn == 1 && nj >= 2) {            // v fragment
        const int dv = (nj - 2) * 16 + q8 * 4;
        const float4 bb = *(const float4*)&bv[h * 64 + dv];
#pragma unroll
        for (int r = 0; r < 4; ++r)
          vt[((size_t)(b_ * 16 + h) * 64 + dv + r) * 512 + s] =
              (bf16)(acc[mi][nj][r] + ((const float*)&bb)[r]);
      } else {
        const bool isq = (wn == 0 && nj < 4);
        const int d = isq ? (nj * 16 + q8 * 4)
                          : (wn == 0 ? (nj - 4) * 16 + q8 * 4
                                     : 32 + nj * 16 + q8 * 4);
        const float* bsrc = isq ? bq : bk;
        const float4 bb = *(const float4*)&bsrc[h * 64 + d];
        bf16x4 o;
        o[0] = (bf16)(acc[mi][nj][0] + bb.x);
        o[1] = (bf16)(acc[mi][nj][1] + bb.y);
        o[2] = (bf16)(acc[mi][nj][2] + bb.z);
        o[3] = (bf16)(acc[mi][nj][3] + bb.w);
        *(bf16x4*)&((isq ? sQ : sK)[tok * 72 + d]) = o;
      }
    }
  }
  asm volatile("s_waitcnt vmcnt(0)" ::: "memory");   // weights (+v stores) done
  __syncthreads();

  // GEMM1: fq = q@Wfq, fk = k@Wfk
  const int rbase = wid * 32;
  bf16x8 aq[2][2], ak[2][2];
#pragma unroll
  for (int i = 0; i < 2; ++i)
#pragma unroll
    for (int kk = 0; kk < 2; ++kk) {
      const int off = (rbase + i * 16 + l4) * 72 + kk * 32 + q8 * 8;
      aq[i][kk] = *(const bf16x8*)&sQ[off];
      ak[i][kk] = *(const bf16x8*)&sK[off];
    }
  f32x4 fqc[2][4] = {}, fkc[2][4] = {};
#pragma unroll
  for (int j = 0; j < 4; ++j) {
    bf16x8 bq0 = *(const bf16x8*)&sWq[(j * 16 + l4) * 72 + q8 * 8];
    bf16x8 bq1 = *(const bf16x8*)&sWq[(j * 16 + l4) * 72 + 32 + q8 * 8];
    bf16x8 bk0 = *(const bf16x8*)&sWk[(j * 16 + l4) * 72 + q8 * 8];
    bf16x8 bk1 = *(const bf16x8*)&sWk[(j * 16 + l4) * 72 + 32 + q8 * 8];
#pragma unroll
    for (int i = 0; i < 2; ++i) {
      fqc[i][j] = MFMA16(aq[i][0], bq0, fqc[i][j]);
      fqc[i][j] = MFMA16(aq[i][1], bq1, fqc[i][j]);
      fkc[i][j] = MFMA16(ak[i][0], bk0, fkc[i][j]);
      fkc[i][j] = MFMA16(ak[i][1], bk1, fkc[i][j]);
    }
  }
  __syncthreads();   // all sWq/sWk reads done; sG may alias them now

#pragma unroll
  for (int j = 0; j < 4; ++j) {
    float bqb = sb[j * 16 + l4], bkb = sb[64 + j * 16 + l4];
#pragma unroll
    for (int i = 0; i < 2; ++i)
#pragma unroll
      for (int r = 0; r < 4; ++r) {
        int row = rbase + i * 16 + q8 * 4 + r;
        float g = (fqc[i][j][r] + bqb) * (fkc[i][j][r] + bkb);
        sG[row * 72 + j * 16 + l4] = (bf16)g;
      }
  }
  __syncthreads();

  // GEMM2: M = G@Wfg
  bf16x8 ag[2][2];
#pragma unroll
  for (int i = 0; i < 2; ++i)
#pragma unroll
    for (int kk = 0; kk < 2; ++kk)
      ag[i][kk] = *(const bf16x8*)&sG[(rbase + i * 16 + l4) * 72 + kk * 32 + q8 * 8];
  f32x4 mc[2][8] = {};
#pragma unroll
  for (int jj = 0; jj < 8; ++jj) {
    bf16x8 bg0 = *(const bf16x8*)&sWg[(jj * 16 + l4) * 72 + q8 * 8];
    bf16x8 bg1 = *(const bf16x8*)&sWg[(jj * 16 + l4) * 72 + 32 + q8 * 8];
#pragma unroll
    for (int i = 0; i < 2; ++i) {
      mc[i][jj] = MFMA16(ag[i][0], bg0, mc[i][jj]);
      mc[i][jj] = MFMA16(ag[i][1], bg1, mc[i][jj]);
    }
  }
  __syncthreads();   // all sG/sWg reads done; Ms may alias them now

#pragma unroll
  for (int jj = 0; jj < 8; ++jj) {
    float bgb = sb[128 + jj * 16 + l4];
#pragma unroll
    for (int i = 0; i < 2; ++i)
#pragma unroll
      for (int r = 0; r < 4; ++r) {
        int row = rbase + i * 16 + q8 * 4 + r;
        float m = mc[i][jj][r] + bgb;
        Ms[row * 136 + jj * 16 + l4] = (bf16)(1.0f / (1.0f + __expf(-m)));
      }
  }
  __syncthreads();

  // apply M (+SC fold into q) and store gated q/k as dense 128B rows
  const float SCg = 0.18033688011112042f;  // log2(e)/8
  const int tl = tid >> 1, half = tid & 1;
  const int mg = m0 + tl;
  bf16* dstg = (half ? kw : qw) + (size_t)mg * 1024 + h * 64;
  const bf16* srcg = (half ? sK : sQ) + tl * 72;
  const bf16* msg_ = Ms + tl * 136 + half * 64;
  const float scl = half ? 1.0f : SCg;
#pragma unroll
  for (int c = 0; c < 8; ++c) {
    bf16x8 v = *(const bf16x8*)&srcg[c * 8];
    bf16x8 m = *(const bf16x8*)&msg_[c * 8];
    bf16x8 o;
#pragma unroll
    for (int e = 0; e < 8; ++e)
      o[e] = (bf16)((float)v[e] * (float)m[e] * scl);
    *(bf16x8*)&dstg[c * 8] = o;
  }
#undef STG_AU
#undef STG_BU
#undef BSRC
#undef LDA2
#undef LDB6
#undef MMQ
#undef PH_PRE
#undef PH_POST
}

// ------------------------------------------------------------- attention
// r10 (kept): Pb aliases Kt -> LDS 35840B -> 4 blocks/CU at 104 VGPR;
// launch_bounds(256,2) is the only spill-free cap. Defer-max, setprio,
// XCD-locality swizzle.
__global__ __launch_bounds__(256, 2) void k_attn(const bf16* __restrict__ qw,
                                                 const bf16* __restrict__ kw,
                                                 const bf16* __restrict__ vt,
                                                 float* __restrict__ out) {
  __shared__ bf16 Kt[128 * 72];       // [key][dk] padded; Pb ALIASES this
  __shared__ bf16 Vt[64 * 136];       // [dk][key] padded (V^T)
  const int tid = threadIdx.x, w = tid >> 6, l = tid & 63;
  const int l4 = l & 15, q8 = l >> 4;
  const int bx = blockIdx.x;
  const int slot = bx >> 3;
  const int qc = slot & 3;
  const int bh = (bx & 7) + 8 * (slot >> 2);
  const int b_ = bh >> 4, h = bh & 15;
  bf16* Pw = Kt + w * 1280;

  bf16x8 qf[2][2];
#pragma unroll
  for (int i = 0; i < 2; ++i)
#pragma unroll
    for (int kk = 0; kk < 2; ++kk) {
      int s = qc * 128 + w * 32 + i * 16 + l4;
      qf[i][kk] = *(const bf16x8*)
          &qw[(((size_t)b_ * 512 + s) * 16 + h) * 64 + kk * 32 + q8 * 8];
    }

  f32x4 o[2][4] = {};
  float mrun[2][4], lrun[2][4];
#pragma unroll
  for (int i = 0; i < 2; ++i)
#pragma unroll
    for (int r = 0; r < 4; ++r) { mrun[i][r] = -3.0e38f; lrun[i][r] = 0.0f; }

  for (int t = 0; t < 4; ++t) {
    __syncthreads();
#pragma unroll
    for (int i = 0; i < 4; ++i) {
      int chunk = i * 256 + tid;
      {  // K tile: straight copy, [key][dk]
        int key = chunk >> 3, c8 = chunk & 7;
        bf16x8 v = *(const bf16x8*)
            &kw[(((size_t)b_ * 512 + t * 128 + key) * 16 + h) * 64 + c8 * 8];
        *(bf16x8*)&Kt[key * 72 + c8 * 8] = v;
      }
      {  // V^T tile: straight copy from global V^T, [dk][key]
        int d = chunk >> 4, c16 = chunk & 15;
        bf16x8 v = *(const bf16x8*)
            &vt[((size_t)bh * 64 + d) * 512 + t * 128 + c16 * 8];
        *(bf16x8*)&Vt[d * 136 + c16 * 8] = v;
      }
    }
    __syncthreads();

    // scores: D[q (2x16)][key (8x16)]
    f32x4 sc[2][8];
    const f32x4 fz = {};
    __builtin_amdgcn_s_setprio(1);
#pragma unroll
    for (int c = 0; c < 8; ++c) {
      bf16x8 kb0 = *(const bf16x8*)&Kt[(c * 16 + l4) * 72 + q8 * 8];
      sc[0][c] = MFMA16(qf[0][0], kb0, fz);
      sc[1][c] = MFMA16(qf[1][0], kb0, fz);
      bf16x8 kb1 = *(const bf16x8*)&Kt[(c * 16 + l4) * 72 + 32 + q8 * 8];
      sc[0][c] = MFMA16(qf[0][1], kb1, sc[0][c]);
      sc[1][c] = MFMA16(qf[1][1], kb1, sc[1][c]);
    }
    __builtin_amdgcn_s_setprio(0);
    __syncthreads();   // all Kt reads done; Pw (aliasing Kt) may be written

    // online softmax (exp2 domain); defer-max (T13, THR=8)
#pragma unroll
    for (int i = 0; i < 2; ++i) {
      float mx[4];
#pragma unroll
      for (int r = 0; r < 4; ++r) {
        float m2 = sc[i][0][r];
#pragma unroll
        for (int c = 1; c < 8; ++c) m2 = fmaxf(m2, sc[i][c][r]);
        m2 = fmaxf(m2, __shfl_xor(m2, 1));
        m2 = fmaxf(m2, __shfl_xor(m2, 2));
        m2 = fmaxf(m2, __shfl_xor(m2, 4));
        m2 = fmaxf(m2, __shfl_xor(m2, 8));
        mx[r] = m2;
      }
      bool grow = false;
#pragma unroll
      for (int r = 0; r < 4; ++r) grow = grow || (mx[r] > mrun[i][r] + 8.0f);
      if (__any(grow)) {
        float al[4];
#pragma unroll
        for (int r = 0; r < 4; ++r) {
          float mn = fmaxf(mrun[i][r], mx[r]);
          al[r] = exp2f(mrun[i][r] - mn);
          mrun[i][r] = mn;
          lrun[i][r] *= al[r];
        }
#pragma unroll
        for (int f = 0; f < 4; ++f)
#pragma unroll
          for (int r = 0; r < 4; ++r) o[i][f][r] *= al[r];
      }
#pragma unroll
      for (int r = 0; r < 4; ++r) {
        float sm = 0.0f;
#pragma unroll
        for (int c = 0; c < 8; ++c) {
          float p = exp2f(sc[i][c][r] - mrun[i][r]);
          sc[i][c][r] = p;
          sm += p;
        }
        sm += __shfl_xor(sm, 1); sm += __shfl_xor(sm, 2);
        sm += __shfl_xor(sm, 4); sm += __shfl_xor(sm, 8);
        lrun[i][r] += sm;
      }
    }

    // PV: C/D-layout P -> LDS (32-key chunks) -> A-layout frags -> MFMA
#pragma unroll
    for (int kk2 = 0; kk2 < 4; ++kk2) {
#pragma unroll
      for (int i = 0; i < 2; ++i)
#pragma unroll
        for (int cc = 0; cc < 2; ++cc) {
          int c = kk2 * 2 + cc;
#pragma unroll
          for (int r = 0; r < 4; ++r)
            Pw[(i * 16 + q8 * 4 + r) * 40 + cc * 16 + l4] = (bf16)sc[i][c][r];
        }
      bf16x8 pa0 = *(const bf16x8*)&Pw[(l4) * 40 + q8 * 8];
      bf16x8 pa1 = *(const bf16x8*)&Pw[(16 + l4) * 40 + q8 * 8];
      __builtin_amdgcn_s_setprio(1);
#pragma unroll
      for (int f = 0; f < 4; ++f) {
        bf16x8 vb = *(const bf16x8*)&Vt[(f * 16 + l4) * 136 + kk2 * 32 + q8 * 8];
        o[0][f] = MFMA16(pa0, vb, o[0][f]);
        o[1][f] = MFMA16(pa1, vb, o[1][f]);
      }
      __builtin_amdgcn_s_setprio(0);
    }
  }

  // epilogue: normalize, write [B,S,E] fp32
#pragma unroll
  for (int i = 0; i < 2; ++i)
#pragma unroll
    for (int r = 0; r < 4; ++r) {
      int srow = qc * 128 + w * 32 + i * 16 + q8 * 4 + r;
      float inv = 1.0f / lrun[i][r];
#pragma unroll
      for (int f = 0; f < 4; ++f)
        out[(((size_t)b_ * 512 + srow) * 16 + h) * 64 + f * 16 + l4] =
            o[i][f][r] * inv;
    }
}

// ---------------------------------------------------------------- launcher
extern "C" void kernel_launch(void* const* d_in, const int* in_sizes, int n_in,
                              void* d_out, int out_size, void* d_ws,
                              size_t ws_size, hipStream_t stream) {
  (void)in_sizes; (void)n_in; (void)out_size; (void)ws_size;
  const float* inp = (const float*)d_in[0];
  const float* Wq  = (const float*)d_in[1];
  const float* bq  = (const float*)d_in[2];
  const float* Wk  = (const float*)d_in[3];
  const float* bk  = (const float*)d_in[4];
  const float* Wv  = (const float*)d_in[5];
  const float* bv  = (const float*)d_in[6];
  const float* Wfq = (const float*)d_in[7];
  const float* bfq = (const float*)d_in[8];
  const float* Wfk = (const float*)d_in[9];
  const float* bfk = (const float*)d_in[10];
  const float* Wfg = (const float*)d_in[11];
  const float* bfg = (const float*)d_in[12];
  float* out = (float*)d_out;

  static bool s_attr = false;
  if (!s_attr) {   // allow 80 KiB dynamic LDS
    (void)hipFuncSetAttribute((const void*)k_proj,
                              hipFuncAttributeMaxDynamicSharedMemorySize,
                              81920);
    s_attr = true;
  }

  char* ws = (char*)d_ws;
  bf16* Xb = (bf16*)(ws);                                // 16 MB
  bf16* WT = (bf16*)(ws + 16777216);                     // 6 MB (3x W^T, contiguous)
  bf16* qw = (bf16*)(ws + 16777216 + 6291456);           // 16 MB [B,S,H,DK]
  bf16* kw = qw + 8388608;                               // 16 MB
  bf16* vt = kw + 8388608;                               // 16 MB [B,H,DK,S]
  // gate image scratch: tail of d_out (37888 B). Written by prep, read by
  // proj, then every out byte is overwritten by attn -> stream-ordered safe.
  bf16* gimg = (bf16*)((char*)out + 33516544);

  k_prep<<<11265, 256, 0, stream>>>(inp, Xb, Wq, Wk, Wv, WT,
                                    Wfq, bfq, Wfk, bfk, Wfg, bfg, gimg);
  k_proj<<<dim3(64, 16), 256, 81920, stream>>>(Xb, WT, bq, bk, bv, gimg,
                                               qw, kw, vt);
  k_attn<<<1024, 256, 0, stream>>>(qw, kw, vt, out);
}

// Round 9
// 216.085 us; speedup vs baseline: 1.1041x; 1.1041x over previous
//
#include <hip/hip_runtime.h>

// GatedQueryAttLayer on MI355X (gfx950)
// B=16, S=512, E=1024, H=16, DK=64
// Pipeline (3 kernels): prep (inp->bf16 + W^T cvt + gate image pack, 16-way) ;
//   fused QKV GEMM + GATING (r12 structure) ; flash attention (r13: shuffle
//   chains hoisted out of the per-tile path -- in-lane grow test + deferred
//   cross-lane l-sum; defer-max, setprio, 4 blocks/CU, XCD swizzle).
// Workspace: 70 MB.

typedef __bf16 bf16;
typedef __bf16 bf16x8 __attribute__((ext_vector_type(8)));
typedef __bf16 bf16x4 __attribute__((ext_vector_type(4)));
typedef float  f32x4  __attribute__((ext_vector_type(4)));

#define MFMA16(a,b,c) __builtin_amdgcn_mfma_f32_16x16x32_bf16((a),(b),(c),0,0,0)

#define GLL16(gp, lp)                                                          \
  __builtin_amdgcn_global_load_lds(                                            \
      (__attribute__((address_space(1))) void*)(void*)(gp),                    \
      (__attribute__((address_space(3))) void*)(lp), 16, 0, 0)

// --------------------------------------------- prep: inp cvt + weight cvt/T
// bx<8192: fp32->bf16 input convert. bx<11264: W^T cvt. bx>=11264 (16 blocks):
// pack gate-weight LDS image (Wfq^T|Wfk^T|Wfg^T padded-72 + fp32 biases) --
// spread 16-way so no single-block serial tail extends the kernel.
__global__ __launch_bounds__(256) void k_prep(const float* __restrict__ in,
                                              bf16* __restrict__ Xb,
                                              const float* __restrict__ Wq,
                                              const float* __restrict__ Wk,
                                              const float* __restrict__ Wv,
                                              bf16* __restrict__ WT,
                                              const float* __restrict__ Wfq,
                                              const float* __restrict__ bfq,
                                              const float* __restrict__ Wfk,
                                              const float* __restrict__ bfk,
                                              const float* __restrict__ Wfg,
                                              const float* __restrict__ bfg,
                                              bf16* __restrict__ gimg) {
  __shared__ float tile[32][33];
  const int bx = blockIdx.x, t = threadIdx.x;
  if (bx < 8192) {                       // conv: fp32 -> bf16, 4 elems/thread
    int i = bx * 256 + t;
    float4 v = ((const float4*)in)[i];
    bf16x4 o;
    o[0] = (bf16)v.x; o[1] = (bf16)v.y; o[2] = (bf16)v.z; o[3] = (bf16)v.w;
    ((bf16x4*)Xb)[i] = o;
  } else if (bx < 11264) {               // weight transpose + cvt
    int r = bx - 8192;
    int mat = r >> 10; r &= 1023;
    int kb = r >> 5, nb = r & 31;
    const float* W = (mat == 0) ? Wq : ((mat == 1) ? Wk : Wv);
    bf16* O = WT + (size_t)mat * (1024 * 1024);
    const int tr = t >> 3, tc = (t & 7) * 4;
    float4 v = *(const float4*)&W[(size_t)(kb * 32 + tr) * 1024 + nb * 32 + tc];
    tile[tr][tc] = v.x; tile[tr][tc + 1] = v.y;
    tile[tr][tc + 2] = v.z; tile[tr][tc + 3] = v.w;
    __syncthreads();
    bf16x4 o;
    o[0] = (bf16)tile[tc][tr];     o[1] = (bf16)tile[tc + 1][tr];
    o[2] = (bf16)tile[tc + 2][tr]; o[3] = (bf16)tile[tc + 3][tr];
    *(bf16x4*)&O[(size_t)(nb * 32 + tr) * 1024 + kb * 32 + tc] = o;
  } else {                               // gate-weight image pack (16 blocks)
    const int p = bx - 11264;            // 0..15
    const int gt = p * 256 + t;          // 0..4095
    {
      int k = gt >> 6, n = gt & 63;
      gimg[n * 72 + k]        = (bf16)Wfq[k * 64 + n];
      gimg[4608 + n * 72 + k] = (bf16)Wfk[k * 64 + n];
    }
#pragma unroll
    for (int e = 0; e < 2; ++e) {
      int idx = gt * 2 + e;              // 0..8191
      int k = idx >> 7, n = idx & 127;
      gimg[9216 + n * 72 + k] = (bf16)Wfg[k * 128 + n];
    }
    if (p == 0) {
      float* fb = (float*)(gimg + 18432);  // byte 36864: packed biases
      if (t < 64) { fb[t] = bfq[t]; fb[64 + t] = bfk[t]; }
      if (t < 128) fb[128 + t] = bfg[t];
    }
  }
}

// ------------------------------------- fused QKV projection + gating GEMM
// r12 (kept): per-head N-tiling {q_h|k_h|v_h}=192; 8-phase counted-vmcnt
// K-loop; gate weights staged from pre-packed image via 9 uniform GLL16s.
__global__ __launch_bounds__(256, 2) void k_proj(const bf16* __restrict__ X,
                                                 const bf16* __restrict__ WT,
                                                 const float* __restrict__ bq,
                                                 const float* __restrict__ bk,
                                                 const float* __restrict__ bv,
                                                 const bf16* __restrict__ gimg,
                                                 bf16* __restrict__ qw,
                                                 bf16* __restrict__ kw,
                                                 bf16* __restrict__ vt) {
  extern __shared__ bf16 lds[];
  bf16* As = lds;            // 2 bufs x [128 rows][64 k] = 32 KiB
  bf16* Bs = lds + 16384;    // 2 bufs x [192 rows][64 k] = 48 KiB

  const int tid = threadIdx.x;
  const int m0 = blockIdx.x * 128;
  const int h  = blockIdx.y;             // head 0..15

  const int l = tid & 63, wid = tid >> 6;
  const int wm = wid >> 1, wn = wid & 1;          // 2M x 2N waves
  const int l4 = l & 15, q8 = l >> 4;
  const int cs0 = (q8 ^ (l4 & 7)) * 8;            // swizzled read col (kk=0)
  const int arow = (wm * 64 + l4) * 64;
  const int brow = (wn * 96 + l4) * 64;

  // staging: linear LDS dest (tid*16B), inverse-swizzled global source
  const int srow = tid >> 3;                      // 0..31 within a 32-row unit
  const int scol = ((tid & 7) ^ (srow & 7)) * 8;
  const bf16* Xs  = X  + (size_t)(m0 + srow) * 1024 + scol;
  const bf16* Wq_ = WT + (size_t)(h * 64 + srow) * 1024 + scol;
  const bf16* Wk_ = Wq_ + (size_t)1024 * 1024;
  const bf16* Wv_ = Wk_ + (size_t)1024 * 1024;
  const int ldst = tid * 8;

#define STG_AU(bf, kt, u)                                                      \
  GLL16(Xs + (size_t)(u) * 32768 + (kt) * 64,                                  \
        As + (bf) * 8192 + (u) * 2048 + ldst)
#define BSRC(u) ((u) < 2 ? Wq_ : ((u) < 4 ? Wk_ : Wv_))
#define STG_BU(bf, kt, u)                                                      \
  GLL16(BSRC(u) + (size_t)((u) & 1) * 32768 + (kt) * 64,                       \
        Bs + (bf) * 12288 + (u) * 2048 + ldst)

  f32x4 acc[4][6] = {};
  bf16x8 aa[2], bb0[6], bb1[6];

#define LDA2(bf, qm, kk)                                                       \
  do {                                                                         \
    _Pragma("unroll") for (int m_ = 0; m_ < 2; ++m_)                           \
        aa[m_] = *(const bf16x8*)&As[(bf) * 8192 + arow + (qm) * 2048 +        \
                                     m_ * 1024 + (cs0 ^ ((kk) * 32))];         \
  } while (0)
#define LDB6(bf, kk, arr)                                                      \
  do {                                                                         \
    _Pragma("unroll") for (int n_ = 0; n_ < 6; ++n_)                           \
        arr[n_] = *(const bf16x8*)&Bs[(bf) * 12288 + brow + n_ * 1024 +        \
                                      (cs0 ^ ((kk) * 32))];                    \
  } while (0)
#define MMQ(qm, arr)                                                           \
  do {                                                                         \
    _Pragma("unroll") for (int m_ = 0; m_ < 2; ++m_)                           \
    _Pragma("unroll") for (int n_ = 0; n_ < 6; ++n_)                           \
        acc[(qm) * 2 + m_][n_] =                                               \
            MFMA16(arr[n_], aa[m_], acc[(qm) * 2 + m_][n_]);                   \
  } while (0)
#define PH_PRE                                                                 \
  __builtin_amdgcn_s_barrier();                                                \
  asm volatile("s_waitcnt lgkmcnt(0)" ::: "memory");                           \
  __builtin_amdgcn_s_setprio(1)
#define PH_POST                                                                \
  __builtin_amdgcn_s_setprio(0);                                               \
  __builtin_amdgcn_s_barrier()

  // prologue: tile0 -> buf0 (A 4u + B 6u); tile1 B (6u) -> buf1.
  STG_AU(0, 0, 0); STG_AU(0, 0, 1); STG_AU(0, 0, 2); STG_AU(0, 0, 3);
  STG_BU(0, 0, 0); STG_BU(0, 0, 1); STG_BU(0, 0, 2);
  STG_BU(0, 0, 3); STG_BU(0, 0, 4); STG_BU(0, 0, 5);
  STG_BU(1, 1, 0); STG_BU(1, 1, 1); STG_BU(1, 1, 2);
  STG_BU(1, 1, 3); STG_BU(1, 1, 4); STG_BU(1, 1, 5);
  asm volatile("s_waitcnt vmcnt(6)" ::: "memory");
  __builtin_amdgcn_s_barrier();

#pragma unroll 1
  for (int i = 0; i < 8; ++i) {
    const int t1 = 2 * i + 1;
    const int t2 = (i < 7) ? 2 * i + 2 : 14;   // clamp: identical-byte restage
    const int t3 = (i < 7) ? 2 * i + 3 : 15;
    // ph1
    LDB6(0, 0, bb0); LDA2(0, 0, 0);
    STG_AU(1, t1, 0); STG_AU(1, t1, 1);
    PH_PRE; MMQ(0, bb0); PH_POST;
    // ph2
    LDB6(0, 1, bb1); LDA2(0, 1, 0);
    STG_AU(1, t1, 2); STG_AU(1, t1, 3);
    PH_PRE; MMQ(1, bb0); PH_POST;
    // ph3
    LDA2(0, 0, 1);
    STG_BU(0, t2, 0); STG_BU(0, t2, 1); STG_BU(0, t2, 2);
    PH_PRE; MMQ(0, bb1); PH_POST;
    // ph4
    LDA2(0, 1, 1);
    STG_BU(0, t2, 3); STG_BU(0, t2, 4); STG_BU(0, t2, 5);
    PH_PRE; MMQ(1, bb1);
    __builtin_amdgcn_s_setprio(0);
    asm volatile("s_waitcnt vmcnt(6)" ::: "memory");
    __builtin_amdgcn_s_barrier();
    // ph5
    LDB6(1, 0, bb0); LDA2(1, 0, 0);
    STG_AU(0, t2, 0); STG_AU(0, t2, 1);
    PH_PRE; MMQ(0, bb0); PH_POST;
    // ph6
    LDB6(1, 1, bb1); LDA2(1, 1, 0);
    STG_AU(0, t2, 2); STG_AU(0, t2, 3);
    PH_PRE; MMQ(1, bb0); PH_POST;
    // ph7
    LDA2(1, 0, 1);
    STG_BU(1, t3, 0); STG_BU(1, t3, 1); STG_BU(1, t3, 2);
    PH_PRE; MMQ(0, bb1); PH_POST;
    // ph8
    LDA2(1, 1, 1);
    STG_BU(1, t3, 3); STG_BU(1, t3, 4); STG_BU(1, t3, 5);
    PH_PRE; MMQ(1, bb1);
    __builtin_amdgcn_s_setprio(0);
    asm volatile("s_waitcnt vmcnt(6)" ::: "memory");
    __builtin_amdgcn_s_barrier();
  }

  // ================= fused gating epilogue (k_gate body) =================
  asm volatile("s_waitcnt vmcnt(0)" ::: "memory");
  __syncthreads();

  char* gb = (char*)lds;                    // 80 KiB budget
  bf16* sQ  = (bf16*)gb;                    // [128][72] biased q   18432 B
  bf16* sK  = (bf16*)(gb + 18432);          // [128][72] biased k   18432 B
  bf16* sWq = (bf16*)(gb + 36864);          // [64][72]              9216 B
  bf16* sWk = (bf16*)(gb + 46080);          // [64][72]              9216 B
  bf16* sWg = (bf16*)(gb + 55296);          // [128][72]            18432 B
  float* sb = (float*)(gb + 73728);         // 256 floats            1024 B
  bf16* sG  = (bf16*)(gb + 36864);          // aliases sWq+sWk (dead post-GEMM1)
  bf16* Ms  = (bf16*)(gb + 36864);          // [128][136] aliases sG+sWg

  // gate weight image -> LDS: 9 uniform GLL16 passes; fly under reg work.
#pragma unroll
  for (int p = 0; p < 9; ++p)
    GLL16(gimg + p * 2048 + tid * 8, (bf16*)(gb + 36864) + p * 2048 + tid * 8);
  sb[tid] = ((const float*)(gimg + 18432))[tid];

  // v store (biased) + biased q/k staged to LDS; acc dead afterwards.
#pragma unroll
  for (int mi = 0; mi < 4; ++mi) {
    const int tok = wm * 64 + mi * 16 + l4;
    const int m = m0 + tok;
    const int b_ = m >> 9, s = m & 511;
#pragma unroll
    for (int nj = 0; nj < 6; ++nj) {
      if (wn == 1 && nj >= 2) {            // v fragment
        const int dv = (nj - 2) * 16 + q8 * 4;
        const float4 bb = *(const float4*)&bv[h * 64 + dv];
#pragma unroll
        for (int r = 0; r < 4; ++r)
          vt[((size_t)(b_ * 16 + h) * 64 + dv + r) * 512 + s] =
              (bf16)(acc[mi][nj][r] + ((const float*)&bb)[r]);
      } else {
        const bool isq = (wn == 0 && nj < 4);
        const int d = isq ? (nj * 16 + q8 * 4)
                          : (wn == 0 ? (nj - 4) * 16 + q8 * 4
                                     : 32 + nj * 16 + q8 * 4);
        const float* bsrc = isq ? bq : bk;
        const float4 bb = *(const float4*)&bsrc[h * 64 + d];
        bf16x4 o;
        o[0] = (bf16)(acc[mi][nj][0] + bb.x);
        o[1] = (bf16)(acc[mi][nj][1] + bb.y);
        o[2] = (bf16)(acc[mi][nj][2] + bb.z);
        o[3] = (bf16)(acc[mi][nj][3] + bb.w);
        *(bf16x4*)&((isq ? sQ : sK)[tok * 72 + d]) = o;
      }
    }
  }
  asm volatile("s_waitcnt vmcnt(0)" ::: "memory");   // weights (+v stores) done
  __syncthreads();

  // GEMM1: fq = q@Wfq, fk = k@Wfk
  const int rbase = wid * 32;
  bf16x8 aq[2][2], ak[2][2];
#pragma unroll
  for (int i = 0; i < 2; ++i)
#pragma unroll
    for (int kk = 0; kk < 2; ++kk) {
      const int off = (rbase + i * 16 + l4) * 72 + kk * 32 + q8 * 8;
      aq[i][kk] = *(const bf16x8*)&sQ[off];
      ak[i][kk] = *(const bf16x8*)&sK[off];
    }
  f32x4 fqc[2][4] = {}, fkc[2][4] = {};
#pragma unroll
  for (int j = 0; j < 4; ++j) {
    bf16x8 bq0 = *(const bf16x8*)&sWq[(j * 16 + l4) * 72 + q8 * 8];
    bf16x8 bq1 = *(const bf16x8*)&sWq[(j * 16 + l4) * 72 + 32 + q8 * 8];
    bf16x8 bk0 = *(const bf16x8*)&sWk[(j * 16 + l4) * 72 + q8 * 8];
    bf16x8 bk1 = *(const bf16x8*)&sWk[(j * 16 + l4) * 72 + 32 + q8 * 8];
#pragma unroll
    for (int i = 0; i < 2; ++i) {
      fqc[i][j] = MFMA16(aq[i][0], bq0, fqc[i][j]);
      fqc[i][j] = MFMA16(aq[i][1], bq1, fqc[i][j]);
      fkc[i][j] = MFMA16(ak[i][0], bk0, fkc[i][j]);
      fkc[i][j] = MFMA16(ak[i][1], bk1, fkc[i][j]);
    }
  }
  __syncthreads();   // all sWq/sWk reads done; sG may alias them now

#pragma unroll
  for (int j = 0; j < 4; ++j) {
    float bqb = sb[j * 16 + l4], bkb = sb[64 + j * 16 + l4];
#pragma unroll
    for (int i = 0; i < 2; ++i)
#pragma unroll
      for (int r = 0; r < 4; ++r) {
        int row = rbase + i * 16 + q8 * 4 + r;
        float g = (fqc[i][j][r] + bqb) * (fkc[i][j][r] + bkb);
        sG[row * 72 + j * 16 + l4] = (bf16)g;
      }
  }
  __syncthreads();

  // GEMM2: M = G@Wfg
  bf16x8 ag[2][2];
#pragma unroll
  for (int i = 0; i < 2; ++i)
#pragma unroll
    for (int kk = 0; kk < 2; ++kk)
      ag[i][kk] = *(const bf16x8*)&sG[(rbase + i * 16 + l4) * 72 + kk * 32 + q8 * 8];
  f32x4 mc[2][8] = {};
#pragma unroll
  for (int jj = 0; jj < 8; ++jj) {
    bf16x8 bg0 = *(const bf16x8*)&sWg[(jj * 16 + l4) * 72 + q8 * 8];
    bf16x8 bg1 = *(const bf16x8*)&sWg[(jj * 16 + l4) * 72 + 32 + q8 * 8];
#pragma unroll
    for (int i = 0; i < 2; ++i) {
      mc[i][jj] = MFMA16(ag[i][0], bg0, mc[i][jj]);
      mc[i][jj] = MFMA16(ag[i][1], bg1, mc[i][jj]);
    }
  }
  __syncthreads();   // all sG/sWg reads done; Ms may alias them now

#pragma unroll
  for (int jj = 0; jj < 8; ++jj) {
    float bgb = sb[128 + jj * 16 + l4];
#pragma unroll
    for (int i = 0; i < 2; ++i)
#pragma unroll
      for (int r = 0; r < 4; ++r) {
        int row = rbase + i * 16 + q8 * 4 + r;
        float m = mc[i][jj][r] + bgb;
        Ms[row * 136 + jj * 16 + l4] = (bf16)(1.0f / (1.0f + __expf(-m)));
      }
  }
  __syncthreads();

  // apply M (+SC fold into q) and store gated q/k as dense 128B rows
  const float SCg = 0.18033688011112042f;  // log2(e)/8
  const int tl = tid >> 1, half = tid & 1;
  const int mg = m0 + tl;
  bf16* dstg = (half ? kw : qw) + (size_t)mg * 1024 + h * 64;
  const bf16* srcg = (half ? sK : sQ) + tl * 72;
  const bf16* msg_ = Ms + tl * 136 + half * 64;
  const float scl = half ? 1.0f : SCg;
#pragma unroll
  for (int c = 0; c < 8; ++c) {
    bf16x8 v = *(const bf16x8*)&srcg[c * 8];
    bf16x8 m = *(const bf16x8*)&msg_[c * 8];
    bf16x8 o;
#pragma unroll
    for (int e = 0; e < 8; ++e)
      o[e] = (bf16)((float)v[e] * (float)m[e] * scl);
    *(bf16x8*)&dstg[c * 8] = o;
  }
#undef STG_AU
#undef STG_BU
#undef BSRC
#undef LDA2
#undef LDB6
#undef MMQ
#undef PH_PRE
#undef PH_POST
}

// ------------------------------------------------------------- attention
// r13: per-tile shuffle chains removed from the steady state.
// (a) grow test uses IN-LANE max only (rowmax>thr <=> __any(lanemax>thr));
//     the 4-deep cross-lane shfl-max chain runs only inside the rare grow
//     branch (tile 0, then ~never).
// (b) l-sum kept as PER-LANE partials (rescale factors are group-uniform);
//     single cross-lane reduce after the tile loop replaces 4x per-tile
//     shfl-add chains. Math identical up to fp add order.
// r10 base kept: Pb aliases Kt (35840B -> 4 blocks/CU), launch_bounds(256,2)
// (the only spill-free cap), setprio, XCD-locality swizzle.
__global__ __launch_bounds__(256, 2) void k_attn(const bf16* __restrict__ qw,
                                                 const bf16* __restrict__ kw,
                                                 const bf16* __restrict__ vt,
                                                 float* __restrict__ out) {
  __shared__ bf16 Kt[128 * 72];       // [key][dk] padded; Pb ALIASES this
  __shared__ bf16 Vt[64 * 136];       // [dk][key] padded (V^T)
  const int tid = threadIdx.x, w = tid >> 6, l = tid & 63;
  const int l4 = l & 15, q8 = l >> 4;
  const int bx = blockIdx.x;
  const int slot = bx >> 3;
  const int qc = slot & 3;
  const int bh = (bx & 7) + 8 * (slot >> 2);
  const int b_ = bh >> 4, h = bh & 15;
  bf16* Pw = Kt + w * 1280;

  bf16x8 qf[2][2];
#pragma unroll
  for (int i = 0; i < 2; ++i)
#pragma unroll
    for (int kk = 0; kk < 2; ++kk) {
      int s = qc * 128 + w * 32 + i * 16 + l4;
      qf[i][kk] = *(const bf16x8*)
          &qw[(((size_t)b_ * 512 + s) * 16 + h) * 64 + kk * 32 + q8 * 8];
    }

  f32x4 o[2][4] = {};
  float mrun[2][4], lrun[2][4];
#pragma unroll
  for (int i = 0; i < 2; ++i)
#pragma unroll
    for (int r = 0; r < 4; ++r) { mrun[i][r] = -3.0e38f; lrun[i][r] = 0.0f; }

  for (int t = 0; t < 4; ++t) {
    __syncthreads();
#pragma unroll
    for (int i = 0; i < 4; ++i) {
      int chunk = i * 256 + tid;
      {  // K tile: straight copy, [key][dk]
        int key = chunk >> 3, c8 = chunk & 7;
        bf16x8 v = *(const bf16x8*)
            &kw[(((size_t)b_ * 512 + t * 128 + key) * 16 + h) * 64 + c8 * 8];
        *(bf16x8*)&Kt[key * 72 + c8 * 8] = v;
      }
      {  // V^T tile: straight copy from global V^T, [dk][key]
        int d = chunk >> 4, c16 = chunk & 15;
        bf16x8 v = *(const bf16x8*)
            &vt[((size_t)bh * 64 + d) * 512 + t * 128 + c16 * 8];
        *(bf16x8*)&Vt[d * 136 + c16 * 8] = v;
      }
    }
    __syncthreads();

    // scores: D[q (2x16)][key (8x16)]
    f32x4 sc[2][8];
    const f32x4 fz = {};
    __builtin_amdgcn_s_setprio(1);
#pragma unroll
    for (int c = 0; c < 8; ++c) {
      bf16x8 kb0 = *(const bf16x8*)&Kt[(c * 16 + l4) * 72 + q8 * 8];
      sc[0][c] = MFMA16(qf[0][0], kb0, fz);
      sc[1][c] = MFMA16(qf[1][0], kb0, fz);
      bf16x8 kb1 = *(const bf16x8*)&Kt[(c * 16 + l4) * 72 + 32 + q8 * 8];
      sc[0][c] = MFMA16(qf[0][1], kb1, sc[0][c]);
      sc[1][c] = MFMA16(qf[1][1], kb1, sc[1][c]);
    }
    __builtin_amdgcn_s_setprio(0);
    __syncthreads();   // all Kt reads done; Pw (aliasing Kt) may be written

    // online softmax (exp2 domain). Steady state: NO cross-lane shuffles.
#pragma unroll
    for (int i = 0; i < 2; ++i) {
      float lmax[4];
#pragma unroll
      for (int r = 0; r < 4; ++r) {
        float m2 = sc[i][0][r];
#pragma unroll
        for (int c = 1; c < 8; ++c) m2 = fmaxf(m2, sc[i][c][r]);
        lmax[r] = m2;                    // in-lane max (lower bound of rowmax)
      }
      bool grow = false;
#pragma unroll
      for (int r = 0; r < 4; ++r) grow = grow || (lmax[r] > mrun[i][r] + 8.0f);
      if (__any(grow)) {                 // rare: tile 0, then ~never
        float al[4];
#pragma unroll
        for (int r = 0; r < 4; ++r) {
          float m2 = lmax[r];
          m2 = fmaxf(m2, __shfl_xor(m2, 1));
          m2 = fmaxf(m2, __shfl_xor(m2, 2));
          m2 = fmaxf(m2, __shfl_xor(m2, 4));
          m2 = fmaxf(m2, __shfl_xor(m2, 8));
          float mn = fmaxf(mrun[i][r], m2);
          al[r] = exp2f(mrun[i][r] - mn);
          mrun[i][r] = mn;
          lrun[i][r] *= al[r];           // per-lane partial rescales too
        }
#pragma unroll
        for (int f = 0; f < 4; ++f)
#pragma unroll
          for (int r = 0; r < 4; ++r) o[i][f][r] *= al[r];
      }
#pragma unroll
      for (int r = 0; r < 4; ++r) {
        float sm = 0.0f;
#pragma unroll
        for (int c = 0; c < 8; ++c) {
          float p = exp2f(sc[i][c][r] - mrun[i][r]);
          sc[i][c][r] = p;
          sm += p;
        }
        lrun[i][r] += sm;                // PER-LANE partial; reduced at end
      }
    }

    // PV: C/D-layout P -> LDS (32-key chunks) -> A-layout frags -> MFMA
#pragma unroll
    for (int kk2 = 0; kk2 < 4; ++kk2) {
#pragma unroll
      for (int i = 0; i < 2; ++i)
#pragma unroll
        for (int cc = 0; cc < 2; ++cc) {
          int c = kk2 * 2 + cc;
#pragma unroll
          for (int r = 0; r < 4; ++r)
            Pw[(i * 16 + q8 * 4 + r) * 40 + cc * 16 + l4] = (bf16)sc[i][c][r];
        }
      bf16x8 pa0 = *(const bf16x8*)&Pw[(l4) * 40 + q8 * 8];
      bf16x8 pa1 = *(const bf16x8*)&Pw[(16 + l4) * 40 + q8 * 8];
      __builtin_amdgcn_s_setprio(1);
#pragma unroll
      for (int f = 0; f < 4; ++f) {
        bf16x8 vb = *(const bf16x8*)&Vt[(f * 16 + l4) * 136 + kk2 * 32 + q8 * 8];
        o[0][f] = MFMA16(pa0, vb, o[0][f]);
        o[1][f] = MFMA16(pa1, vb, o[1][f]);
      }
      __builtin_amdgcn_s_setprio(0);
    }
  }

  // deferred cross-lane l reduction (once, not per tile)
#pragma unroll
  for (int i = 0; i < 2; ++i)
#pragma unroll
    for (int r = 0; r < 4; ++r) {
      float s = lrun[i][r];
      s += __shfl_xor(s, 1); s += __shfl_xor(s, 2);
      s += __shfl_xor(s, 4); s += __shfl_xor(s, 8);
      lrun[i][r] = s;
    }

  // epilogue: normalize, write [B,S,E] fp32
#pragma unroll
  for (int i = 0; i < 2; ++i)
#pragma unroll
    for (int r = 0; r < 4; ++r) {
      int srow = qc * 128 + w * 32 + i * 16 + q8 * 4 + r;
      float inv = 1.0f / lrun[i][r];
#pragma unroll
      for (int f = 0; f < 4; ++f)
        out[(((size_t)b_ * 512 + srow) * 16 + h) * 64 + f * 16 + l4] =
            o[i][f][r] * inv;
    }
}

// ---------------------------------------------------------------- launcher
extern "C" void kernel_launch(void* const* d_in, const int* in_sizes, int n_in,
                              void* d_out, int out_size, void* d_ws,
                              size_t ws_size, hipStream_t stream) {
  (void)in_sizes; (void)n_in; (void)out_size; (void)ws_size;
  const float* inp = (const float*)d_in[0];
  const float* Wq  = (const float*)d_in[1];
  const float* bq  = (const float*)d_in[2];
  const float* Wk  = (const float*)d_in[3];
  const float* bk  = (const float*)d_in[4];
  const float* Wv  = (const float*)d_in[5];
  const float* bv  = (const float*)d_in[6];
  const float* Wfq = (const float*)d_in[7];
  const float* bfq = (const float*)d_in[8];
  const float* Wfk = (const float*)d_in[9];
  const float* bfk = (const float*)d_in[10];
  const float* Wfg = (const float*)d_in[11];
  const float* bfg = (const float*)d_in[12];
  float* out = (float*)d_out;

  static bool s_attr = false;
  if (!s_attr) {   // allow 80 KiB dynamic LDS
    (void)hipFuncSetAttribute((const void*)k_proj,
                              hipFuncAttributeMaxDynamicSharedMemorySize,
                              81920);
    s_attr = true;
  }

  char* ws = (char*)d_ws;
  bf16* Xb = (bf16*)(ws);                                // 16 MB
  bf16* WT = (bf16*)(ws + 16777216);                     // 6 MB (3x W^T, contiguous)
  bf16* qw = (bf16*)(ws + 16777216 + 6291456);           // 16 MB [B,S,H,DK]
  bf16* kw = qw + 8388608;                               // 16 MB
  bf16* vt = kw + 8388608;                               // 16 MB [B,H,DK,S]
  // gate image scratch: tail of d_out (37888 B). Written by prep, read by
  // proj, then every out byte is overwritten by attn -> stream-ordered safe.
  bf16* gimg = (bf16*)((char*)out + 33516544);

  k_prep<<<11280, 256, 0, stream>>>(inp, Xb, Wq, Wk, Wv, WT,
                                    Wfq, bfq, Wfk, bfk, Wfg, bfg, gimg);
  k_proj<<<dim3(64, 16), 256, 81920, stream>>>(Xb, WT, bq, bk, bv, gimg,
                                               qw, kw, vt);
  k_attn<<<1024, 256, 0, stream>>>(qw, kw, vt, out);
}